// Round 8
// baseline (783.024 us; speedup 1.0000x reference)
//
#include <hip/hip_runtime.h>
#include <cstdint>
#include <cmath>

typedef unsigned short u16;
typedef __attribute__((ext_vector_type(4))) float f32x4;
typedef __attribute__((ext_vector_type(8))) short bf16x8;

#define D_MODEL 1024
#define SEQ     2048
#define BATCH   4
#define NHEAD   16
#define MTOT    (BATCH*SEQ)      /* 8192 rows */
#define NXE     ((size_t)MTOT * D_MODEL)   /* 8,388,608 elems per plane */

static_assert(sizeof(bf16x8) == 16, "frag size");

__device__ __forceinline__ float bf2f(u16 u) {
    union { uint32_t i; float f; } v; v.i = ((uint32_t)u) << 16; return v.f;
}
__device__ __forceinline__ u16 f2bf(float x) {
    union { float f; uint32_t i; } v; v.f = x;
    uint32_t r = (v.i + 0x7FFFu + ((v.i >> 16) & 1u)) >> 16;   // RNE
    return (u16)r;
}
__device__ __forceinline__ u16 f2bf_trunc(float x) {          // cheap: P only
    union { float f; uint32_t i; } v; v.f = x;
    return (u16)(v.i >> 16);
}

typedef const __attribute__((address_space(1))) void* gptr_t;
typedef __attribute__((address_space(3))) void* sptr_t;
__device__ __forceinline__ void gload_lds16(const void* g, void* l) {
    __builtin_amdgcn_global_load_lds((gptr_t)g, (sptr_t)l, 16, 0, 0);
}

// ---------------------------------------------------------------------------
// Precondition-failure flood: d_out is fp32; absmax report encodes 2^e.
// ---------------------------------------------------------------------------
__global__ __launch_bounds__(256) void diag_write(float* __restrict__ out, float v) {
    size_t i = (size_t)blockIdx.x * 256 + threadIdx.x;
    for (; i < NXE; i += (size_t)gridDim.x * 256) out[i] = v;
}

// ---------------------------------------------------------------------------
// Dtype sniffer (validated r3/r5/r6: inputs are fp32 -> flag=0).
// ---------------------------------------------------------------------------
__global__ void detect_dtype(const u16* __restrict__ x, int* __restrict__ flag) {
    __shared__ int cnt;
    if (threadIdx.x == 0) cnt = 0;
    __syncthreads();
    int c = 0;
#pragma unroll
    for (int k = 0; k < 16; ++k) {
        u16 e = x[2 * (threadIdx.x * 16 + k)];
        int ex = (e >> 7) & 0xFF;
        if (e == 0 || (ex >= 100 && ex <= 140)) ++c;
    }
    atomicAdd(&cnt, c);
    __syncthreads();
    if (threadIdx.x == 0) *flag = (cnt >= 3500) ? 1 : 0;
}

// ---------------------------------------------------------------------------
// Normalize inputs to bf16 planes (fp32 -> RNE downconvert; bf16 -> copy).
// ---------------------------------------------------------------------------
struct CvtArgs { const void* src[9]; u16* dst[9]; int n[9]; };

__global__ __launch_bounds__(256) void cvt_all(CvtArgs a, const int* __restrict__ flag) {
    const int seg = blockIdx.y;
    const int n = a.n[seg];
    const int i = (blockIdx.x * 256 + threadIdx.x) * 8;
    if (i >= n) return;
    u16* d = a.dst[seg] + i;
    if (*flag) {
        *(uint4*)d = *(const uint4*)((const u16*)a.src[seg] + i);
    } else {
        const float* s = (const float*)a.src[seg] + i;
        u16 tmp[8];
#pragma unroll
        for (int k = 0; k < 8; ++k) tmp[k] = f2bf(s[k]);
        *(uint4*)d = *(uint4*)tmp;
    }
}

// ---------------------------------------------------------------------------
// MFMA GEMM (m97 structure, 128x128, BK=32) — correctness proven (r6/r7).
// ---------------------------------------------------------------------------
template <typename OutT>
__device__ __forceinline__ void gemm_body(
    const u16* __restrict__ A, const u16* __restrict__ W,
    const u16* __restrict__ bias, OutT* __restrict__ C,
    int M, int N, int K)
{
    __shared__ __align__(16) u16 As[128 * 32];
    __shared__ __align__(16) u16 Bs[128 * 32];

    const int t    = threadIdx.x;
    const int wave = t >> 6;
    const int ln   = t & 15;
    const int qd   = (t >> 4) & 3;
    const int m0   = blockIdx.x * 128;
    const int n0   = blockIdx.y * 128;
    const int wm   = (wave >> 1) * 64;
    const int wn   = (wave & 1) * 64;

    const int srow = t >> 2;
    const int scol = (t & 3) * 8;
    const u16* gA = A + (size_t)(m0 + srow) * K + scol;
    const u16* gB = W + (size_t)(n0 + srow) * K + scol;
    u16* lA = &As[wave * 512];
    u16* lB = &Bs[wave * 512];

    f32x4 acc[4][4] = {};

    for (int k0 = 0; k0 < K; k0 += 32) {
        __syncthreads();
        gload_lds16(gA + k0,                   lA);
        gload_lds16(gA + (size_t)64 * K + k0,  lA + 2048);
        gload_lds16(gB + k0,                   lB);
        gload_lds16(gB + (size_t)64 * K + k0,  lB + 2048);
        __syncthreads();

        bf16x8 af[4], bfr[4];
#pragma unroll
        for (int i = 0; i < 4; ++i)
            af[i] = *(const bf16x8*)&As[(wm + i * 16 + ln) * 32 + qd * 8];
#pragma unroll
        for (int j = 0; j < 4; ++j)
            bfr[j] = *(const bf16x8*)&Bs[(wn + j * 16 + ln) * 32 + qd * 8];
#pragma unroll
        for (int i = 0; i < 4; ++i)
#pragma unroll
            for (int j = 0; j < 4; ++j)
                acc[i][j] = __builtin_amdgcn_mfma_f32_16x16x32_bf16(
                    af[i], bfr[j], acc[i][j], 0, 0, 0);
    }

    float bv[4];
#pragma unroll
    for (int j = 0; j < 4; ++j) bv[j] = bf2f(bias[n0 + wn + j * 16 + ln]);

#pragma unroll
    for (int i = 0; i < 4; ++i)
#pragma unroll
        for (int r = 0; r < 4; ++r) {
            int row = m0 + wm + i * 16 + qd * 4 + r;
            OutT* crow = C + (size_t)row * N + n0 + wn + ln;
#pragma unroll
            for (int j = 0; j < 4; ++j) {
                float v = acc[i][j][r] + bv[j];
                if constexpr (sizeof(OutT) == 2) crow[j * 16] = f2bf(v);
                else                             crow[j * 16] = v;
            }
        }
}

__global__ __launch_bounds__(256) void gemm_qkv(
    const u16* __restrict__ A,
    const u16* __restrict__ W0, const u16* __restrict__ W1, const u16* __restrict__ W2,
    const u16* __restrict__ b0, const u16* __restrict__ b1, const u16* __restrict__ b2,
    u16* __restrict__ C0, u16* __restrict__ C1, u16* __restrict__ C2,
    int M, int N, int K)
{
    const u16* W; const u16* bias; u16* C;
    if (blockIdx.z == 0)      { W = W0; bias = b0; C = C0; }
    else if (blockIdx.z == 1) { W = W1; bias = b1; C = C1; }
    else                      { W = W2; bias = b2; C = C2; }
    gemm_body<u16>(A, W, bias, C, M, N, K);
}

__global__ __launch_bounds__(256) void gemm_final_f32(
    const u16* __restrict__ A, const u16* __restrict__ W,
    const u16* __restrict__ bias, float* __restrict__ C, int M, int N, int K)
{
    gemm_body<float>(A, W, bias, C, M, N, K);
}

// ---------------------------------------------------------------------------
// Flash attention, causal — ONE WAVE PER BLOCK (round-8 restructure).
// Block = 64 threads; block (x,y) owns q rows [qw*64, qw*64+64) of head bh,
// qw = 31 - blockIdx.x (longest blocks dispatched first).  Loops only over
// its own kt <= qw tiles: no inter-wave barriers, no idle tiles.
// LDS: V tile 8 KB + P 8 KB = 16 KB -> 10 blocks/CU; grid 2048 blocks ~ all
// co-resident (8/CU).  Numerics identical to the r6-proven kernel except
// P stored with truncation instead of RNE (error << threshold margin).
// ---------------------------------------------------------------------------
__global__ __launch_bounds__(64) void flash_attn(
    const u16* __restrict__ Qg, const u16* __restrict__ Kg,
    const u16* __restrict__ Vg, u16* __restrict__ Og)
{
    __shared__ __align__(16) u16 Vsh[64 * 64];
    __shared__ __align__(16) u16 Psh[64 * 64];

    const int lane = threadIdx.x;       // 0..63
    const int ln   = lane & 15;
    const int qd   = lane >> 4;

    const int qw = 31 - blockIdx.x;     // reversed: longest first
    const int bh = blockIdx.y;
    const int b  = bh >> 4;
    const int h  = bh & 15;
    const int h0 = h * 64;
    const size_t rowBase = (size_t)b * SEQ * D_MODEL;
    const int qw0 = qw * 64;

    // ---- Q fragments straight from global: A[m=lane&15][k=quad*8+e] ----
    bf16x8 qf[4][2];
#pragma unroll
    for (int i = 0; i < 4; ++i)
#pragma unroll
        for (int ks = 0; ks < 2; ++ks)
            qf[i][ks] = *(const bf16x8*)(Qg + rowBase
                + (size_t)(qw0 + i * 16 + ln) * D_MODEL + h0 + ks * 32 + qd * 8);

    float m_run[4][4], l_run[4][4];
#pragma unroll
    for (int i = 0; i < 4; ++i)
#pragma unroll
        for (int r = 0; r < 4; ++r) { m_run[i][r] = -30000.0f; l_run[i][r] = 0.f; }
    f32x4 oacc[4][4] = {};

    for (int kt = 0; kt <= qw; ++kt) {
        __syncthreads();                 // prev iter's Vsh/Psh reads done
        // ---- stage V tile (64x64): 512 uint4, 8 per lane ----
#pragma unroll
        for (int p = 0; p < 8; ++p) {
            const int idx = p * 64 + lane;
            const int vr  = idx >> 3;
            const int vc  = (idx & 7) * 8;
            *(uint4*)&Vsh[idx * 8] = *(const uint4*)(Vg + rowBase
                + (size_t)(kt * 64 + vr) * D_MODEL + h0 + vc);
        }

        // ---- S = Q K^T (K fragments straight from global) ----
        f32x4 sacc[4][4] = {};
#pragma unroll
        for (int ks = 0; ks < 2; ++ks) {
            bf16x8 kf[4];
#pragma unroll
            for (int j = 0; j < 4; ++j)
                kf[j] = *(const bf16x8*)(Kg + rowBase
                    + (size_t)(kt * 64 + j * 16 + ln) * D_MODEL + h0 + ks * 32 + qd * 8);
#pragma unroll
            for (int i = 0; i < 4; ++i)
#pragma unroll
                for (int j = 0; j < 4; ++j)
                    sacc[i][j] = __builtin_amdgcn_mfma_f32_16x16x32_bf16(
                        qf[i][ks], kf[j], sacc[i][j], 0, 0, 0);
        }

        // ---- scale + causal mask + online softmax ----
        const bool diag = (kt == qw);
#pragma unroll
        for (int i = 0; i < 4; ++i)
#pragma unroll
            for (int r = 0; r < 4; ++r) {
                const int qpos = qw0 + i * 16 + qd * 4 + r;
                float mx = -30000.0f;
#pragma unroll
                for (int j = 0; j < 4; ++j) {
                    float s = sacc[i][j][r] * 0.125f;
                    if (diag) {
                        int kpos = kt * 64 + j * 16 + ln;
                        if (kpos > qpos) s = -30000.0f;
                    }
                    sacc[i][j][r] = s;
                    mx = fmaxf(mx, s);
                }
                mx = fmaxf(mx, __shfl_xor(mx, 1));
                mx = fmaxf(mx, __shfl_xor(mx, 2));
                mx = fmaxf(mx, __shfl_xor(mx, 4));
                mx = fmaxf(mx, __shfl_xor(mx, 8));

                const float mo = m_run[i][r];
                const float mn = fmaxf(mo, mx);
                const float alpha = __expf(mo - mn);
                m_run[i][r] = mn;
                l_run[i][r] *= alpha;
#pragma unroll
                for (int j = 0; j < 4; ++j) oacc[i][j][r] *= alpha;

                float rs = 0.f;
#pragma unroll
                for (int j = 0; j < 4; ++j) {
                    float p = __expf(sacc[i][j][r] - mn);
                    rs += p;
                    Psh[(i * 16 + qd * 4 + r) * 64 + j * 16 + ln] = f2bf_trunc(p);
                }
                rs += __shfl_xor(rs, 1);
                rs += __shfl_xor(rs, 2);
                rs += __shfl_xor(rs, 4);
                rs += __shfl_xor(rs, 8);
                l_run[i][r] += rs;
            }

        __syncthreads();                 // V staged + P visible (wave-internal)

        // ---- O += P V ----
#pragma unroll
        for (int ks = 0; ks < 2; ++ks) {
            bf16x8 pa[4];
#pragma unroll
            for (int i = 0; i < 4; ++i)
                pa[i] = *(const bf16x8*)&Psh[(i * 16 + ln) * 64 + ks * 32 + qd * 8];
#pragma unroll
            for (int j = 0; j < 4; ++j) {
                bf16x8 vb;
#pragma unroll
                for (int e = 0; e < 8; ++e)
                    vb[e] = (short)Vsh[(ks * 32 + qd * 8 + e) * 64 + j * 16 + ln];
#pragma unroll
                for (int i = 0; i < 4; ++i)
                    oacc[i][j] = __builtin_amdgcn_mfma_f32_16x16x32_bf16(
                        pa[i], vb, oacc[i][j], 0, 0, 0);
            }
        }
    }

    // ---- epilogue: O / l ----
#pragma unroll
    for (int i = 0; i < 4; ++i)
#pragma unroll
        for (int r = 0; r < 4; ++r) {
            const float inv = 1.f / l_run[i][r];
            const int qrow = qw0 + i * 16 + qd * 4 + r;
            u16* orow = Og + rowBase + (size_t)qrow * D_MODEL + h0 + ln;
#pragma unroll
            for (int j = 0; j < 4; ++j)
                orow[j * 16] = f2bf(oacc[i][j][r] * inv);
        }
}

// ---------------------------------------------------------------------------
static inline bool ranges_overlap(const void* a, size_t an, const void* b, size_t bn) {
    uintptr_t x0 = (uintptr_t)a, x1 = x0 + an;
    uintptr_t y0 = (uintptr_t)b, y1 = y0 + bn;
    return x0 < y1 && y0 < x1;
}

extern "C" void kernel_launch(void* const* d_in, const int* in_sizes, int n_in,
                              void* d_out, int out_size, void* d_ws, size_t ws_size,
                              hipStream_t stream)
{
    int e = 0;
    const int expect[9] = { 8388608, 1048576, 1024, 1048576, 1024,
                            1048576, 1024, 1048576, 1024 };
    if (n_in != 9) e = 59;
    if (!e) for (int i = 0; i < 9; ++i)
        if (in_sizes[i] != expect[i]) { e = 60 + i; break; }
    if (!e && out_size != (int)NXE) e = 53;
    if (!e && ranges_overlap(d_ws, ws_size, d_out, (size_t)out_size * 4)) e = 55;

    const size_t NX = NXE;
    const size_t NW = (size_t)D_MODEL * D_MODEL;
    const size_t NB = D_MODEL;

    // ws need: flag(64) + 4 weights + 4 biases + K + V = 40.0 MB (proven safe r7).
    const size_t need = (64 + 4 * NW + 4 * NB + 2 * NX) * 2;
    if (!e && ws_size < need) e = 50;
    if (e) { diag_write<<<2048, 256, 0, stream>>>((float*)d_out, ldexpf(1.0f, e)); return; }

    // ws layout (u16 elems): flag | Wq Wk Wv Wo | bq bk bv bo | K | V
    u16* ws   = (u16*)d_ws;
    int* flag = (int*)ws;
    u16* Wqb  = ws + 64;
    u16* Wkb  = Wqb + NW;
    u16* Wvb  = Wkb + NW;
    u16* Wob  = Wvb + NW;
    u16* bqb  = Wob + NW;
    u16* bkb  = bqb + NB;
    u16* bvb  = bkb + NB;
    u16* bob  = bvb + NB;
    u16* Kw   = bob + NB;
    u16* Vw   = Kw  + NX;

    // d_out (32 MB) packing: [xb / A : 16 MB][Q : 16 MB].
    u16* xb = (u16*)d_out;           // x_bf16; dead after QKV gemm
    u16* Qw = xb + NX;               // Q plane (upper half)
    u16* Aw = xb;                    // attention out reuses lower half
    float* Fout = (float*)Kw;        // final fp32 out over dead K+V (32 MB)

    detect_dtype<<<1, 256, 0, stream>>>((const u16*)d_in[0], flag);

    CvtArgs ca;
    const void* srcs[9] = { d_in[0], d_in[1], d_in[3], d_in[5], d_in[7],
                            d_in[2], d_in[4], d_in[6], d_in[8] };
    u16* dsts[9] = { xb, Wqb, Wkb, Wvb, Wob, bqb, bkb, bvb, bob };
    int  ns[9]   = { (int)NX, (int)NW, (int)NW, (int)NW, (int)NW,
                     (int)NB, (int)NB, (int)NB, (int)NB };
    for (int i = 0; i < 9; ++i) { ca.src[i] = srcs[i]; ca.dst[i] = dsts[i]; ca.n[i] = ns[i]; }
    cvt_all<<<dim3((unsigned)((NX + 2047) / 2048), 9), 256, 0, stream>>>(ca, flag);

    gemm_qkv<<<dim3(MTOT / 128, D_MODEL / 128, 3), 256, 0, stream>>>(
        xb, Wqb, Wkb, Wvb, bqb, bkb, bvb, Qw, Kw, Vw, MTOT, D_MODEL, D_MODEL);

    flash_attn<<<dim3(SEQ / 64, BATCH * NHEAD), 64, 0, stream>>>(Qw, Kw, Vw, Aw);

    gemm_final_f32<<<dim3(MTOT / 128, D_MODEL / 128), 256, 0, stream>>>(
        Aw, Wob, bob, Fout, MTOT, D_MODEL, D_MODEL);

    hipMemcpyAsync(d_out, Fout, NX * sizeof(float), hipMemcpyDeviceToDevice, stream);
}

// Round 9
// 442.842 us; speedup vs baseline: 1.7682x; 1.7682x over previous
//
#include <hip/hip_runtime.h>
#include <cstdint>
#include <cmath>

typedef unsigned short u16;
typedef __attribute__((ext_vector_type(4))) float f32x4;
typedef __attribute__((ext_vector_type(8))) short bf16x8;

#define D_MODEL 1024
#define SEQ     2048
#define BATCH   4
#define NHEAD   16
#define MTOT    (BATCH*SEQ)      /* 8192 rows */
#define NXE     ((size_t)MTOT * D_MODEL)   /* 8,388,608 elems per plane */

static_assert(sizeof(bf16x8) == 16, "frag size");

__device__ __forceinline__ float bf2f(u16 u) {
    union { uint32_t i; float f; } v; v.i = ((uint32_t)u) << 16; return v.f;
}
__device__ __forceinline__ u16 f2bf(float x) {
    union { float f; uint32_t i; } v; v.f = x;
    uint32_t r = (v.i + 0x7FFFu + ((v.i >> 16) & 1u)) >> 16;   // RNE
    return (u16)r;
}
__device__ __forceinline__ u16 f2bf_trunc(float x) {          // cheap: P only
    union { float f; uint32_t i; } v; v.f = x;
    return (u16)(v.i >> 16);
}

typedef const __attribute__((address_space(1))) void* gptr_t;
typedef __attribute__((address_space(3))) void* sptr_t;
__device__ __forceinline__ void gload_lds16(const void* g, void* l) {
    __builtin_amdgcn_global_load_lds((gptr_t)g, (sptr_t)l, 16, 0, 0);
}

// ---------------------------------------------------------------------------
// Precondition-failure flood: d_out is fp32; absmax report encodes 2^e.
// ---------------------------------------------------------------------------
__global__ __launch_bounds__(256) void diag_write(float* __restrict__ out, float v) {
    size_t i = (size_t)blockIdx.x * 256 + threadIdx.x;
    for (; i < NXE; i += (size_t)gridDim.x * 256) out[i] = v;
}

// ---------------------------------------------------------------------------
// Dtype sniffer (validated r3/r5/r6: inputs are fp32 -> flag=0).
// ---------------------------------------------------------------------------
__global__ void detect_dtype(const u16* __restrict__ x, int* __restrict__ flag) {
    __shared__ int cnt;
    if (threadIdx.x == 0) cnt = 0;
    __syncthreads();
    int c = 0;
#pragma unroll
    for (int k = 0; k < 16; ++k) {
        u16 e = x[2 * (threadIdx.x * 16 + k)];
        int ex = (e >> 7) & 0xFF;
        if (e == 0 || (ex >= 100 && ex <= 140)) ++c;
    }
    atomicAdd(&cnt, c);
    __syncthreads();
    if (threadIdx.x == 0) *flag = (cnt >= 3500) ? 1 : 0;
}

// ---------------------------------------------------------------------------
// Normalize inputs to bf16 planes (fp32 -> RNE downconvert; bf16 -> copy).
// ---------------------------------------------------------------------------
struct CvtArgs { const void* src[9]; u16* dst[9]; int n[9]; };

__global__ __launch_bounds__(256) void cvt_all(CvtArgs a, const int* __restrict__ flag) {
    const int seg = blockIdx.y;
    const int n = a.n[seg];
    const int i = (blockIdx.x * 256 + threadIdx.x) * 8;
    if (i >= n) return;
    u16* d = a.dst[seg] + i;
    if (*flag) {
        *(uint4*)d = *(const uint4*)((const u16*)a.src[seg] + i);
    } else {
        const float* s = (const float*)a.src[seg] + i;
        u16 tmp[8];
#pragma unroll
        for (int k = 0; k < 8; ++k) tmp[k] = f2bf(s[k]);
        *(uint4*)d = *(uint4*)tmp;
    }
}

// ---------------------------------------------------------------------------
// MFMA GEMM (m97 structure, 128x128, BK=32) — correctness proven (r6/r7/r8).
// ---------------------------------------------------------------------------
template <typename OutT>
__device__ __forceinline__ void gemm_body(
    const u16* __restrict__ A, const u16* __restrict__ W,
    const u16* __restrict__ bias, OutT* __restrict__ C,
    int M, int N, int K)
{
    __shared__ __align__(16) u16 As[128 * 32];
    __shared__ __align__(16) u16 Bs[128 * 32];

    const int t    = threadIdx.x;
    const int wave = t >> 6;
    const int ln   = t & 15;
    const int qd   = (t >> 4) & 3;
    const int m0   = blockIdx.x * 128;
    const int n0   = blockIdx.y * 128;
    const int wm   = (wave >> 1) * 64;
    const int wn   = (wave & 1) * 64;

    const int srow = t >> 2;
    const int scol = (t & 3) * 8;
    const u16* gA = A + (size_t)(m0 + srow) * K + scol;
    const u16* gB = W + (size_t)(n0 + srow) * K + scol;
    u16* lA = &As[wave * 512];
    u16* lB = &Bs[wave * 512];

    f32x4 acc[4][4] = {};

    for (int k0 = 0; k0 < K; k0 += 32) {
        __syncthreads();
        gload_lds16(gA + k0,                   lA);
        gload_lds16(gA + (size_t)64 * K + k0,  lA + 2048);
        gload_lds16(gB + k0,                   lB);
        gload_lds16(gB + (size_t)64 * K + k0,  lB + 2048);
        __syncthreads();

        bf16x8 af[4], bfr[4];
#pragma unroll
        for (int i = 0; i < 4; ++i)
            af[i] = *(const bf16x8*)&As[(wm + i * 16 + ln) * 32 + qd * 8];
#pragma unroll
        for (int j = 0; j < 4; ++j)
            bfr[j] = *(const bf16x8*)&Bs[(wn + j * 16 + ln) * 32 + qd * 8];
#pragma unroll
        for (int i = 0; i < 4; ++i)
#pragma unroll
            for (int j = 0; j < 4; ++j)
                acc[i][j] = __builtin_amdgcn_mfma_f32_16x16x32_bf16(
                    af[i], bfr[j], acc[i][j], 0, 0, 0);
    }

    float bv[4];
#pragma unroll
    for (int j = 0; j < 4; ++j) bv[j] = bf2f(bias[n0 + wn + j * 16 + ln]);

#pragma unroll
    for (int i = 0; i < 4; ++i)
#pragma unroll
        for (int r = 0; r < 4; ++r) {
            int row = m0 + wm + i * 16 + qd * 4 + r;
            OutT* crow = C + (size_t)row * N + n0 + wn + ln;
#pragma unroll
            for (int j = 0; j < 4; ++j) {
                float v = acc[i][j][r] + bv[j];
                if constexpr (sizeof(OutT) == 2) crow[j * 16] = f2bf(v);
                else                             crow[j * 16] = v;
            }
        }
}

__global__ __launch_bounds__(256) void gemm_qkv(
    const u16* __restrict__ A,
    const u16* __restrict__ W0, const u16* __restrict__ W1, const u16* __restrict__ W2,
    const u16* __restrict__ b0, const u16* __restrict__ b1, const u16* __restrict__ b2,
    u16* __restrict__ C0, u16* __restrict__ C1, u16* __restrict__ C2,
    int M, int N, int K)
{
    const u16* W; const u16* bias; u16* C;
    if (blockIdx.z == 0)      { W = W0; bias = b0; C = C0; }
    else if (blockIdx.z == 1) { W = W1; bias = b1; C = C1; }
    else                      { W = W2; bias = b2; C = C2; }
    gemm_body<u16>(A, W, bias, C, M, N, K);
}

__global__ __launch_bounds__(256) void gemm_final_f32(
    const u16* __restrict__ A, const u16* __restrict__ W,
    const u16* __restrict__ bias, float* __restrict__ C, int M, int N, int K)
{
    gemm_body<float>(A, W, bias, C, M, N, K);
}

// ---------------------------------------------------------------------------
// Flash attention, causal — round 9: 1 wave/block, 32 q-rows/wave (register
// diet: ~150 unified VGPR -> ~3 waves/SIMD), XOR-swizzled LDS (bank-conflict
// free V gather and P round-trip).
//   Vsh[k][d ^ ((k>>3)&3)<<4]   (8 KB)
//   Psh[q][c ^ ((q>>2)&3)<<4]   (4 KB)
// Grid: x = 64 q-tiles (reversed, longest first), y = 64 (b*h).
// ---------------------------------------------------------------------------
__global__ __launch_bounds__(64) void flash_attn(
    const u16* __restrict__ Qg, const u16* __restrict__ Kg,
    const u16* __restrict__ Vg, u16* __restrict__ Og)
{
    __shared__ __align__(16) u16 Vsh[64 * 64];
    __shared__ __align__(16) u16 Psh[32 * 64];

    const int lane = threadIdx.x;       // 0..63
    const int ln   = lane & 15;
    const int qd   = lane >> 4;

    const int qw = 63 - blockIdx.x;     // q-tile (32 rows), longest first
    const int bh = blockIdx.y;
    const int b  = bh >> 4;
    const int h  = bh & 15;
    const int h0 = h * 64;
    const size_t rowBase = (size_t)b * SEQ * D_MODEL;
    const int qw0 = qw * 32;
    const int ktMax = qw >> 1;          // last K-tile (only one needing mask)

    // ---- Q fragments straight from global: A[m=ln][k=qd*8+e] ----
    bf16x8 qf[2][2];
#pragma unroll
    for (int i = 0; i < 2; ++i)
#pragma unroll
        for (int ks = 0; ks < 2; ++ks)
            qf[i][ks] = *(const bf16x8*)(Qg + rowBase
                + (size_t)(qw0 + i * 16 + ln) * D_MODEL + h0 + ks * 32 + qd * 8);

    float m_run[2][4], l_run[2][4];
#pragma unroll
    for (int i = 0; i < 2; ++i)
#pragma unroll
        for (int r = 0; r < 4; ++r) { m_run[i][r] = -30000.0f; l_run[i][r] = 0.f; }
    f32x4 oacc[2][4] = {};

    for (int kt = 0; kt <= ktMax; ++kt) {
        __syncthreads();                 // prev iter's Vsh/Psh reads done
        // ---- stage V tile (64x64) swizzled: 8 uint4 per lane ----
#pragma unroll
        for (int p = 0; p < 8; ++p) {
            const int idx = p * 64 + lane;
            const int vr  = idx >> 3;                 // 0..63
            const int vc  = (idx & 7) * 8;            // 0,8,..,56
            const int vcs = vc ^ (((vr >> 3) & 3) << 4);
            *(uint4*)&Vsh[vr * 64 + vcs] = *(const uint4*)(Vg + rowBase
                + (size_t)(kt * 64 + vr) * D_MODEL + h0 + vc);
        }

        // ---- S = Q K^T (K fragments straight from global) ----
        f32x4 sacc[2][4] = {};
#pragma unroll
        for (int ks = 0; ks < 2; ++ks) {
            bf16x8 kf[4];
#pragma unroll
            for (int j = 0; j < 4; ++j)
                kf[j] = *(const bf16x8*)(Kg + rowBase
                    + (size_t)(kt * 64 + j * 16 + ln) * D_MODEL + h0 + ks * 32 + qd * 8);
#pragma unroll
            for (int i = 0; i < 2; ++i)
#pragma unroll
                for (int j = 0; j < 4; ++j)
                    sacc[i][j] = __builtin_amdgcn_mfma_f32_16x16x32_bf16(
                        qf[i][ks], kf[j], sacc[i][j], 0, 0, 0);
        }

        // ---- scale (+ mask on the diagonal tile only) ----
        if (kt == ktMax) {
#pragma unroll
            for (int i = 0; i < 2; ++i)
#pragma unroll
                for (int r = 0; r < 4; ++r) {
                    const int qpos = qw0 + i * 16 + qd * 4 + r;
#pragma unroll
                    for (int j = 0; j < 4; ++j) {
                        const int kpos = kt * 64 + j * 16 + ln;
                        float s = sacc[i][j][r] * 0.125f;
                        sacc[i][j][r] = (kpos > qpos) ? -30000.0f : s;
                    }
                }
        } else {
#pragma unroll
            for (int i = 0; i < 2; ++i)
#pragma unroll
                for (int j = 0; j < 4; ++j)
#pragma unroll
                    for (int r = 0; r < 4; ++r)
                        sacc[i][j][r] *= 0.125f;
        }

        // ---- online softmax (per q-row, stats replicated over 16-lane group) ----
#pragma unroll
        for (int i = 0; i < 2; ++i)
#pragma unroll
            for (int r = 0; r < 4; ++r) {
                float mx = fmaxf(fmaxf(sacc[i][0][r], sacc[i][1][r]),
                                 fmaxf(sacc[i][2][r], sacc[i][3][r]));
                mx = fmaxf(mx, __shfl_xor(mx, 1));
                mx = fmaxf(mx, __shfl_xor(mx, 2));
                mx = fmaxf(mx, __shfl_xor(mx, 4));
                mx = fmaxf(mx, __shfl_xor(mx, 8));

                const float mo = m_run[i][r];
                const float mn = fmaxf(mo, mx);
                const float alpha = __expf(mo - mn);
                m_run[i][r] = mn;
                l_run[i][r] *= alpha;
#pragma unroll
                for (int j = 0; j < 4; ++j) oacc[i][j][r] *= alpha;

                const int prow = i * 16 + qd * 4 + r;         // q row in tile
                const int pswz = qd << 4;                     // ((prow>>2)&3)<<4
                float rs = 0.f;
#pragma unroll
                for (int j = 0; j < 4; ++j) {
                    float p = __expf(sacc[i][j][r] - mn);
                    rs += p;
                    Psh[prow * 64 + ((j * 16 + ln) ^ pswz)] = f2bf_trunc(p);
                }
                rs += __shfl_xor(rs, 1);
                rs += __shfl_xor(rs, 2);
                rs += __shfl_xor(rs, 4);
                rs += __shfl_xor(rs, 8);
                l_run[i][r] += rs;
            }

        __syncthreads();                 // V staged + P visible

        // ---- O += P V ----
#pragma unroll
        for (int ks = 0; ks < 2; ++ks) {
            bf16x8 pa[2];                // A-frags of P: row = i*16+ln
#pragma unroll
            for (int i = 0; i < 2; ++i) {
                const int prow = i * 16 + ln;
                const int pswz = ((ln >> 2) & 3) << 4;        // ((prow>>2)&3)<<4
                pa[i] = *(const bf16x8*)&Psh[prow * 64 + ((ks * 32 + qd * 8) ^ pswz)];
            }
#pragma unroll
            for (int j = 0; j < 4; ++j) {
                const int vswz = qd << 4;   // ((k>>3)&3)<<4, k = ks*32+qd*8+e
                bf16x8 vb;                  // B-frag of V: n = d = j*16+ln
#pragma unroll
                for (int e = 0; e < 8; ++e)
                    vb[e] = (short)Vsh[(ks * 32 + qd * 8 + e) * 64
                                       + ((j * 16 + ln) ^ vswz)];
#pragma unroll
                for (int i = 0; i < 2; ++i)
                    oacc[i][j] = __builtin_amdgcn_mfma_f32_16x16x32_bf16(
                        pa[i], vb, oacc[i][j], 0, 0, 0);
            }
        }
    }

    // ---- epilogue: O / l ----
#pragma unroll
    for (int i = 0; i < 2; ++i)
#pragma unroll
        for (int r = 0; r < 4; ++r) {
            const float inv = 1.f / l_run[i][r];
            const int qrow = qw0 + i * 16 + qd * 4 + r;
            u16* orow = Og + rowBase + (size_t)qrow * D_MODEL + h0 + ln;
#pragma unroll
            for (int j = 0; j < 4; ++j)
                orow[j * 16] = f2bf(oacc[i][j][r] * inv);
        }
}

// ---------------------------------------------------------------------------
static inline bool ranges_overlap(const void* a, size_t an, const void* b, size_t bn) {
    uintptr_t x0 = (uintptr_t)a, x1 = x0 + an;
    uintptr_t y0 = (uintptr_t)b, y1 = y0 + bn;
    return x0 < y1 && y0 < x1;
}

extern "C" void kernel_launch(void* const* d_in, const int* in_sizes, int n_in,
                              void* d_out, int out_size, void* d_ws, size_t ws_size,
                              hipStream_t stream)
{
    int e = 0;
    const int expect[9] = { 8388608, 1048576, 1024, 1048576, 1024,
                            1048576, 1024, 1048576, 1024 };
    if (n_in != 9) e = 59;
    if (!e) for (int i = 0; i < 9; ++i)
        if (in_sizes[i] != expect[i]) { e = 60 + i; break; }
    if (!e && out_size != (int)NXE) e = 53;
    if (!e && ranges_overlap(d_ws, ws_size, d_out, (size_t)out_size * 4)) e = 55;

    const size_t NX = NXE;
    const size_t NW = (size_t)D_MODEL * D_MODEL;
    const size_t NB = D_MODEL;

    // ws need: flag(64) + 4 weights + 4 biases + K + V = 40.0 MB (proven safe r7/r8).
    const size_t need = (64 + 4 * NW + 4 * NB + 2 * NX) * 2;
    if (!e && ws_size < need) e = 50;
    if (e) { diag_write<<<2048, 256, 0, stream>>>((float*)d_out, ldexpf(1.0f, e)); return; }

    // ws layout (u16 elems): flag | Wq Wk Wv Wo | bq bk bv bo | K | V
    u16* ws   = (u16*)d_ws;
    int* flag = (int*)ws;
    u16* Wqb  = ws + 64;
    u16* Wkb  = Wqb + NW;
    u16* Wvb  = Wkb + NW;
    u16* Wob  = Wvb + NW;
    u16* bqb  = Wob + NW;
    u16* bkb  = bqb + NB;
    u16* bvb  = bkb + NB;
    u16* bob  = bvb + NB;
    u16* Kw   = bob + NB;
    u16* Vw   = Kw  + NX;

    // d_out (32 MB) packing: [xb / A : 16 MB][Q : 16 MB].
    u16* xb = (u16*)d_out;           // x_bf16; dead after QKV gemm
    u16* Qw = xb + NX;               // Q plane (upper half)
    u16* Aw = xb;                    // attention out reuses lower half
    float* Fout = (float*)Kw;        // final fp32 out over dead K+V (32 MB)

    detect_dtype<<<1, 256, 0, stream>>>((const u16*)d_in[0], flag);

    CvtArgs ca;
    const void* srcs[9] = { d_in[0], d_in[1], d_in[3], d_in[5], d_in[7],
                            d_in[2], d_in[4], d_in[6], d_in[8] };
    u16* dsts[9] = { xb, Wqb, Wkb, Wvb, Wob, bqb, bkb, bvb, bob };
    int  ns[9]   = { (int)NX, (int)NW, (int)NW, (int)NW, (int)NW,
                     (int)NB, (int)NB, (int)NB, (int)NB };
    for (int i = 0; i < 9; ++i) { ca.src[i] = srcs[i]; ca.dst[i] = dsts[i]; ca.n[i] = ns[i]; }
    cvt_all<<<dim3((unsigned)((NX + 2047) / 2048), 9), 256, 0, stream>>>(ca, flag);

    gemm_qkv<<<dim3(MTOT / 128, D_MODEL / 128, 3), 256, 0, stream>>>(
        xb, Wqb, Wkb, Wvb, bqb, bkb, bvb, Qw, Kw, Vw, MTOT, D_MODEL, D_MODEL);

    flash_attn<<<dim3(SEQ / 32, BATCH * NHEAD), 64, 0, stream>>>(Qw, Kw, Vw, Aw);

    gemm_final_f32<<<dim3(MTOT / 128, D_MODEL / 128), 256, 0, stream>>>(
        Aw, Wob, bob, Fout, MTOT, D_MODEL, D_MODEL);

    hipMemcpyAsync(d_out, Fout, NX * sizeof(float), hipMemcpyDeviceToDevice, stream);
}